// Round 1
// 240.680 us; speedup vs baseline: 1.0334x; 1.0334x over previous
//
#include <hip/hip_runtime.h>
#include <hip/hip_bf16.h>
#include <stdint.h>

#define F_DIM 256
#define H_DIM 384
#define L_DIM 64
#define O_DIM 16
#define E_NUM 5
#define BM 64

#define XK_STRIDE 264   // bf16 elems (256 + 8 pad)
#define H_STRIDE 392    // bf16 elems (384 + 8 pad)
#define LAT_STRIDE 65   // f32 elems (64 + 1 pad)
#define MU_STRIDE 328   // bf16 elems (320 + 8 pad)

// LDS layout (bytes):
//   [0, 33792)        Xs  [64][264] bf16   (dead after GEMM1)
//   [0, 50176)        Hs  [64][392] bf16   (aliases Xs; dead after GEMM2)
//   [0, 41984)        mus [64][328] bf16   (aliases Hs)
//   [50176, 66816)    latT [64][65] f32
//   [66816, 68096)    phis 320 int
// total 68096 B -> 2 blocks/CU (136192 <= 163840)
#define LATT_OFF 50176
#define PHIS_OFF 66816
#define SMEM_BYTES 68096

typedef short bf16x8 __attribute__((ext_vector_type(8)));
typedef float f32x4 __attribute__((ext_vector_type(4)));

__device__ __forceinline__ unsigned short f2bf(float f) {
    union { float f; unsigned int u; } v; v.f = f;
    unsigned int u = v.u;
    return (unsigned short)((u + 0x7FFFu + ((u >> 16) & 1u)) >> 16);
}

__device__ __forceinline__ unsigned int pk2(float a, float b) {
#if defined(__has_builtin)
#if __has_builtin(__builtin_amdgcn_cvt_pk_bf16_f32)
    typedef __bf16 bf2 __attribute__((ext_vector_type(2)));
    bf2 p = __builtin_amdgcn_cvt_pk_bf16_f32(a, b);
    union { bf2 v; unsigned int u; } c; c.v = p;
    return c.u;
#else
    return (unsigned int)f2bf(a) | ((unsigned int)f2bf(b) << 16);
#endif
#else
    return (unsigned int)f2bf(a) | ((unsigned int)f2bf(b) << 16);
#endif
}

__device__ __forceinline__ uint2 cvt4(float4 v) {
    uint2 r; r.x = pk2(v.x, v.y); r.y = pk2(v.z, v.w); return r;
}

__device__ __forceinline__ float sigmoidf(float x) {
    return __builtin_amdgcn_rcpf(1.0f + __builtin_amdgcn_exp2f(-1.44269504088896f * x));
}

// ============================ prep ============================
// Unchanged: weights are written in MFMA A-fragment order:
//   Wf[tile][ks][lane][8]  (tile = 16 output-rows, ks = 32 k's, lane = q*16+c)
//   element j of lane (q,c) = W^T[tile*16 + c][ks*32 + q*8 + j]
// blocks 0..95:   W1 (256x384 f,h) -> W1f (24 tiles, 8 ks)
// blocks 96..119: W2 (384x64  h,l) -> W2f (4 tiles, 12 ks)
// block 120:      pi (5x64x16)     -> piTf (1 tile, 10 ks), pre-scaled 1/E
__global__ void prep_kernel(const float* __restrict__ W1, const float* __restrict__ W2,
                            const float* __restrict__ pi,
                            unsigned short* __restrict__ W1f,
                            unsigned short* __restrict__ W2f,
                            unsigned short* __restrict__ piTf) {
    __shared__ float tile[32][33];   // [k_local][row_local]
    const int b = blockIdx.x;
    const int tid = threadIdx.x;
    const int tx = tid & 31, ty = tid >> 5;  // ty 0..7

    if (b < 120) {
        int ks, t0, nks;
        unsigned short* dst;
        if (b < 96) {
            const int fb = b / 12, hb = b % 12;       // k-tile, row-tile-pair
            #pragma unroll
            for (int s = 0; s < 32; s += 8)
                tile[ty + s][tx] = W1[(size_t)(fb * 32 + ty + s) * H_DIM + hb * 32 + tx];
            ks = fb; t0 = hb * 2; nks = 8; dst = W1f;
        } else {
            const int bb = b - 96, hb = bb / 2, lb = bb % 2;
            #pragma unroll
            for (int s = 0; s < 32; s += 8)
                tile[ty + s][tx] = W2[(size_t)(hb * 32 + ty + s) * L_DIM + lb * 32 + tx];
            ks = hb; t0 = lb * 2; nks = 12; dst = W2f;
        }
        __syncthreads();
        const int t_local = tid >> 7;
        const int r = (tid * 2) & 255;
        const int lane = r >> 2;
        const int e2b = r & 3;            // 0 or 2
        const int q = lane >> 4, c = lane & 15;
        const int f0 = q * 8 + e2b * 2;   // k_local base (4 consecutive)
        const int hl = t_local * 16 + c;  // row_local
        uint2 v;
        v.x = pk2(tile[f0 + 0][hl], tile[f0 + 1][hl]);
        v.y = pk2(tile[f0 + 2][hl], tile[f0 + 3][hl]);
        const size_t off = ((size_t)((t0 + t_local) * nks + ks) * 64 + lane) * 8 + e2b * 2;
        *(uint2*)(dst + off) = v;
    } else {
        for (int i = tid; i < O_DIM * E_NUM * L_DIM; i += 256) {
            const int j = i & 7, lane = (i >> 3) & 63, ks = i >> 9;
            const int q = lane >> 4, c = lane & 15;
            const int k = ks * 32 + q * 8 + j;
            piTf[i] = f2bf(pi[k * O_DIM + c] * 0.2f);
        }
    }
}

// ============================ fused ============================
// BM=64 rows per block, 512 threads (8 waves), 2 blocks/CU (LDS-limited).
// __launch_bounds__(512,4): cap 128 VGPR/wave -- REQUIRED for 16 waves/CU
// (129 regs would drop to 3 waves/SIMD -> only 1 block resident).
__global__ __launch_bounds__(512, 4) void fused_kernel(
    const float* __restrict__ X,
    const unsigned short* __restrict__ W1f,
    const float* __restrict__ b1,
    const unsigned short* __restrict__ W2f,
    const float* __restrict__ b2,
    const int* __restrict__ phi,
    const unsigned short* __restrict__ piTf,
    float* __restrict__ out) {

    __shared__ __align__(16) unsigned char smem[SMEM_BYTES];
    unsigned short* Xs  = (unsigned short*)smem;            // [64][264]
    unsigned short* Hs  = (unsigned short*)smem;            // [64][392] (after Xs dead)
    unsigned short* mus = (unsigned short*)smem;            // [64][328] (after Hs dead)
    float*          latT = (float*)(smem + LATT_OFF);       // [64][65]
    int*            phis = (int*)(smem + PHIS_OFF);         // 320 ints

    const int tid  = threadIdx.x;
    const int wave = tid >> 6;
    const int lane = tid & 63;
    const int q    = lane >> 4;
    const int c    = lane & 15;
    const int row0 = blockIdx.x * BM;

    if (tid < E_NUM * L_DIM) phis[tid] = phi[tid];

    // ---- stage X tile: 8 rows per wave, all 8 loads in flight at once
    {
        float4 t0[8];
        #pragma unroll
        for (int i = 0; i < 8; ++i)
            t0[i] = *(const float4*)(X + (size_t)(row0 + wave * 8 + i) * F_DIM + lane * 4);
        #pragma unroll
        for (int i = 0; i < 8; ++i)
            *(uint2*)&Xs[(wave * 8 + i) * XK_STRIDE + lane * 4] = cvt4(t0[i]);
    }

    // prefetch ks=0 A-fragments (hide W1f L2 latency behind the barrier)
    bf16x8 af0[3];
    #pragma unroll
    for (int i = 0; i < 3; ++i)
        af0[i] = *(const bf16x8*)(W1f + ((size_t)((wave * 3 + i) * 8 + 0) * 64 + lane) * 8);

    __syncthreads();   // B1: Xs + phis ready

    // ================= GEMM1: D[n][m] = sum_k W1T[n][k] * Xs[m][k] =================
    // wave owns n-chunk of 48 (tiles wave*3 .. wave*3+2), all 4 m-tiles.
    f32x4 acc[3][4];
    #pragma unroll
    for (int i = 0; i < 3; ++i)
        #pragma unroll
        for (int j = 0; j < 4; ++j)
            acc[i][j] = (f32x4){0.f, 0.f, 0.f, 0.f};

    {   // ks = 0 (peeled, uses prefetched af0)
        bf16x8 bf0[4];
        #pragma unroll
        for (int j = 0; j < 4; ++j)
            bf0[j] = *(const bf16x8*)&Xs[(j * 16 + c) * XK_STRIDE + q * 8];
        #pragma unroll
        for (int i = 0; i < 3; ++i)
            #pragma unroll
            for (int j = 0; j < 4; ++j)
                acc[i][j] = __builtin_amdgcn_mfma_f32_16x16x32_bf16(af0[i], bf0[j], acc[i][j], 0, 0, 0);
    }
    #pragma unroll 2
    for (int ks = 1; ks < 8; ++ks) {
        bf16x8 af[3];
        #pragma unroll
        for (int i = 0; i < 3; ++i)
            af[i] = *(const bf16x8*)(W1f + ((size_t)((wave * 3 + i) * 8 + ks) * 64 + lane) * 8);
        bf16x8 bf_[4];
        #pragma unroll
        for (int j = 0; j < 4; ++j)
            bf_[j] = *(const bf16x8*)&Xs[(j * 16 + c) * XK_STRIDE + ks * 32 + q * 8];
        #pragma unroll
        for (int i = 0; i < 3; ++i)
            #pragma unroll
            for (int j = 0; j < 4; ++j)
                acc[i][j] = __builtin_amdgcn_mfma_f32_16x16x32_bf16(af[i], bf_[j], acc[i][j], 0, 0, 0);
    }
    __syncthreads();   // B2: Xs reads done; Hs (aliases) may be written

    // prefetch W2 fragments now -- in flight across the sigmoid phase + B3
    const int lt = wave >> 1;          // l-tile for GEMM2
    bf16x8 wfrag[12];
    #pragma unroll
    for (int ks = 0; ks < 12; ++ks)
        wfrag[ks] = *(const bf16x8*)(W2f + ((size_t)(lt * 12 + ks) * 64 + lane) * 8);

    #pragma unroll
    for (int i = 0; i < 3; ++i) {
        const int n0 = wave * 48 + i * 16 + q * 4;
        float4 bv = *(const float4*)(b1 + n0);
        #pragma unroll
        for (int j = 0; j < 4; ++j) {
            const int m = j * 16 + c;
            uint2 h2;
            h2.x = pk2(sigmoidf(acc[i][j][0] + bv.x), sigmoidf(acc[i][j][1] + bv.y));
            h2.y = pk2(sigmoidf(acc[i][j][2] + bv.z), sigmoidf(acc[i][j][3] + bv.w));
            *(uint2*)&Hs[m * H_STRIDE + n0] = h2;
        }
    }
    __syncthreads();   // B3: Hs complete

    // ================= GEMM2: D[l][m] = sum_h W2T[l][h] * Hs[m][h] =================
    // wave (lt = wave>>1) does l-tile lt, m-tiles {2*(wave&1), 2*(wave&1)+1}
    {
        const int mbase = (wave & 1) * 2;
        f32x4 acc2[2];
        acc2[0] = (f32x4){0.f, 0.f, 0.f, 0.f};
        acc2[1] = (f32x4){0.f, 0.f, 0.f, 0.f};
        #pragma unroll
        for (int ks = 0; ks < 12; ++ks) {
            #pragma unroll
            for (int j = 0; j < 2; ++j) {
                bf16x8 bf_ = *(const bf16x8*)&Hs[((mbase + j) * 16 + c) * H_STRIDE + ks * 32 + q * 8];
                acc2[j] = __builtin_amdgcn_mfma_f32_16x16x32_bf16(wfrag[ks], bf_, acc2[j], 0, 0, 0);
            }
        }
        const float4 b2v = *(const float4*)(b2 + lt * 16 + q * 4);
        #pragma unroll
        for (int j = 0; j < 2; ++j) {
            const int m = (mbase + j) * 16 + c;
            #pragma unroll
            for (int rg = 0; rg < 4; ++rg) {
                const int l = lt * 16 + q * 4 + rg;
                latT[l * LAT_STRIDE + m] = sigmoidf(acc2[j][rg] + ((const float*)&b2v)[rg]);
            }
        }
    }
    __syncthreads();   // B4: latT complete; Hs dead -> mus writable

    // ================= stage 3a: tree routing =================
    // wave e (< 5) handles estimator e across all 64 rows (r = lane).
    if (wave < E_NUM) {
        const int e = wave;
        const int r = lane;
        float mu[64];
        mu[0] = 1.0f;
        #pragma unroll
        for (int lev = 0; lev < 6; ++lev) {
            const int w = 1 << lev;
            #pragma unroll
            for (int i = w - 1; i >= 0; --i) {
                float d = latT[phis[e * 64 + w + i] * LAT_STRIDE + r];
                float m = mu[i];
                mu[2 * i + 1] = m - m * d;
                mu[2 * i]     = m * d;
            }
        }
        #pragma unroll
        for (int j8 = 0; j8 < 8; ++j8) {
            bf16x8 v;
            #pragma unroll
            for (int t = 0; t < 4; ++t) {
                unsigned int p = pk2(mu[j8 * 8 + 2 * t], mu[j8 * 8 + 2 * t + 1]);
                v[2 * t]     = (short)(p & 0xFFFF);
                v[2 * t + 1] = (short)(p >> 16);
            }
            *((bf16x8*)&mus[r * MU_STRIDE + e * 64 + j8 * 8]) = v;
        }
    }
    __syncthreads();   // B5: mus complete

    // ================= stage 3b: out[m][o] = sum_k mus[m][k] * piT[o][k] =================
    if (wave < 4) {
        const int mt = wave;
        bf16x8 pfrag[10];
        #pragma unroll
        for (int ks = 0; ks < 10; ++ks)
            pfrag[ks] = *(const bf16x8*)(piTf + ((size_t)ks * 64 + lane) * 8);
        f32x4 acc3 = (f32x4){0.f, 0.f, 0.f, 0.f};
        #pragma unroll
        for (int ks = 0; ks < 10; ++ks) {
            bf16x8 af = *((const bf16x8*)&mus[(mt * 16 + c) * MU_STRIDE + ks * 32 + q * 8]);
            acc3 = __builtin_amdgcn_mfma_f32_16x16x32_bf16(af, pfrag[ks], acc3, 0, 0, 0);
        }
        #pragma unroll
        for (int rg = 0; rg < 4; ++rg) {
            const int m = mt * 16 + q * 4 + rg;
            out[(size_t)(row0 + m) * O_DIM + c] = acc3[rg];
        }
    }
}

extern "C" void kernel_launch(void* const* d_in, const int* in_sizes, int n_in,
                              void* d_out, int out_size, void* d_ws, size_t ws_size,
                              hipStream_t stream) {
    (void)in_sizes; (void)n_in; (void)out_size; (void)ws_size;
    const float* X  = (const float*)d_in[0];
    const float* W1 = (const float*)d_in[1];
    const float* b1 = (const float*)d_in[2];
    const float* W2 = (const float*)d_in[3];
    const float* b2 = (const float*)d_in[4];
    const int*   phi = (const int*)d_in[5];
    const float* pi  = (const float*)d_in[6];
    float* out = (float*)d_out;

    unsigned short* W1f  = (unsigned short*)d_ws;                           // 196608 B
    unsigned short* W2f  = (unsigned short*)((char*)d_ws + 196608);         //  49152 B
    unsigned short* piTf = (unsigned short*)((char*)d_ws + 196608 + 49152); //  10240 B

    prep_kernel<<<121, 256, 0, stream>>>(W1, W2, pi, W1f, W2f, piTf);

    const int nblocks = 131072 / BM;  // 2048
    fused_kernel<<<nblocks, 512, 0, stream>>>(X, W1f, b1, W2f, b2, phi, piTf, out);
}

// Round 2
// 240.219 us; speedup vs baseline: 1.0354x; 1.0019x over previous
//
#include <hip/hip_runtime.h>
#include <hip/hip_bf16.h>
#include <stdint.h>

#define F_DIM 256
#define H_DIM 384
#define L_DIM 64
#define O_DIM 16
#define E_NUM 5
#define BM 64

#define XK_STRIDE 264   // bf16 elems (256 + 8 pad)
#define H_STRIDE 392    // bf16 elems (384 + 8 pad)
#define LAT_STRIDE 65   // f32 elems (64 + 1 pad)
#define MU_STRIDE 328   // bf16 elems (320 + 8 pad)

// LDS layout (bytes):
//   [0, 33792)        Xs  [64][264] bf16   (dead after GEMM1)
//   [0, 50176)        Hs  [64][392] bf16   (aliases Xs; dead after GEMM2)
//   [0, 41984)        mus [64][328] bf16   (aliases Hs)
//   [50176, 66816)    latT [64][65] f32
//   [66816, 68096)    phis 320 int
// total 68096 B -> 2 blocks/CU (136192 <= 163840)
#define LATT_OFF 50176
#define PHIS_OFF 66816
#define SMEM_BYTES 68096

typedef short bf16x8 __attribute__((ext_vector_type(8)));
typedef float f32x4 __attribute__((ext_vector_type(4)));

__device__ __forceinline__ unsigned short f2bf(float f) {
    union { float f; unsigned int u; } v; v.f = f;
    unsigned int u = v.u;
    return (unsigned short)((u + 0x7FFFu + ((u >> 16) & 1u)) >> 16);
}

__device__ __forceinline__ unsigned int pk2(float a, float b) {
#if defined(__has_builtin)
#if __has_builtin(__builtin_amdgcn_cvt_pk_bf16_f32)
    typedef __bf16 bf2 __attribute__((ext_vector_type(2)));
    bf2 p = __builtin_amdgcn_cvt_pk_bf16_f32(a, b);
    union { bf2 v; unsigned int u; } c; c.v = p;
    return c.u;
#else
    return (unsigned int)f2bf(a) | ((unsigned int)f2bf(b) << 16);
#endif
#else
    return (unsigned int)f2bf(a) | ((unsigned int)f2bf(b) << 16);
#endif
}

__device__ __forceinline__ uint2 cvt4(float4 v) {
    uint2 r; r.x = pk2(v.x, v.y); r.y = pk2(v.z, v.w); return r;
}

__device__ __forceinline__ float sigmoidf(float x) {
    return __builtin_amdgcn_rcpf(1.0f + __builtin_amdgcn_exp2f(-1.44269504088896f * x));
}

// ============================ prep ============================
// Unchanged: weights are written in MFMA A-fragment order:
//   Wf[tile][ks][lane][8]  (tile = 16 output-rows, ks = 32 k's, lane = q*16+c)
//   element j of lane (q,c) = W^T[tile*16 + c][ks*32 + q*8 + j]
// blocks 0..95:   W1 (256x384 f,h) -> W1f (24 tiles, 8 ks)
// blocks 96..119: W2 (384x64  h,l) -> W2f (4 tiles, 12 ks)
// block 120:      pi (5x64x16)     -> piTf (1 tile, 10 ks), pre-scaled 1/E
__global__ void prep_kernel(const float* __restrict__ W1, const float* __restrict__ W2,
                            const float* __restrict__ pi,
                            unsigned short* __restrict__ W1f,
                            unsigned short* __restrict__ W2f,
                            unsigned short* __restrict__ piTf) {
    __shared__ float tile[32][33];   // [k_local][row_local]
    const int b = blockIdx.x;
    const int tid = threadIdx.x;
    const int tx = tid & 31, ty = tid >> 5;  // ty 0..7

    if (b < 120) {
        int ks, t0, nks;
        unsigned short* dst;
        if (b < 96) {
            const int fb = b / 12, hb = b % 12;       // k-tile, row-tile-pair
            #pragma unroll
            for (int s = 0; s < 32; s += 8)
                tile[ty + s][tx] = W1[(size_t)(fb * 32 + ty + s) * H_DIM + hb * 32 + tx];
            ks = fb; t0 = hb * 2; nks = 8; dst = W1f;
        } else {
            const int bb = b - 96, hb = bb / 2, lb = bb % 2;
            #pragma unroll
            for (int s = 0; s < 32; s += 8)
                tile[ty + s][tx] = W2[(size_t)(hb * 32 + ty + s) * L_DIM + lb * 32 + tx];
            ks = hb; t0 = lb * 2; nks = 12; dst = W2f;
        }
        __syncthreads();
        const int t_local = tid >> 7;
        const int r = (tid * 2) & 255;
        const int lane = r >> 2;
        const int e2b = r & 3;            // 0 or 2
        const int q = lane >> 4, c = lane & 15;
        const int f0 = q * 8 + e2b * 2;   // k_local base (4 consecutive)
        const int hl = t_local * 16 + c;  // row_local
        uint2 v;
        v.x = pk2(tile[f0 + 0][hl], tile[f0 + 1][hl]);
        v.y = pk2(tile[f0 + 2][hl], tile[f0 + 3][hl]);
        const size_t off = ((size_t)((t0 + t_local) * nks + ks) * 64 + lane) * 8 + e2b * 2;
        *(uint2*)(dst + off) = v;
    } else {
        for (int i = tid; i < O_DIM * E_NUM * L_DIM; i += 256) {
            const int j = i & 7, lane = (i >> 3) & 63, ks = i >> 9;
            const int q = lane >> 4, c = lane & 15;
            const int k = ks * 32 + q * 8 + j;
            piTf[i] = f2bf(pi[k * O_DIM + c] * 0.2f);
        }
    }
}

// ============================ fused ============================
// BM=64 rows per block, 512 threads (8 waves), 2 blocks/CU (LDS-limited).
// __launch_bounds__(512,4): cap 128 VGPR/wave -- REQUIRED for 16 waves/CU.
// Convoy-break: the 2 co-resident blocks otherwise run phase-locked
// (both MFMA together, both stalled together -> 47% busy). A one-time
// ~8k-cycle skew on half the first-round blocks anti-phases each pair;
// the skew self-perpetuates across block rounds.
__global__ __launch_bounds__(512, 4) void fused_kernel(
    const float* __restrict__ X,
    const unsigned short* __restrict__ W1f,
    const float* __restrict__ b1,
    const unsigned short* __restrict__ W2f,
    const float* __restrict__ b2,
    const int* __restrict__ phi,
    const unsigned short* __restrict__ piTf,
    float* __restrict__ out) {

    __shared__ __align__(16) unsigned char smem[SMEM_BYTES];
    unsigned short* Xs  = (unsigned short*)smem;            // [64][264]
    unsigned short* Hs  = (unsigned short*)smem;            // [64][392] (after Xs dead)
    unsigned short* mus = (unsigned short*)smem;            // [64][328] (after Hs dead)
    float*          latT = (float*)(smem + LATT_OFF);       // [64][65]
    int*            phis = (int*)(smem + PHIS_OFF);         // 320 ints

    // ---- convoy-breaking skew: only the first-round blocks (idx < 512),
    // and only the second slot-half (bit 8), sleep once (~8128 cycles).
    if (blockIdx.x < 512 && ((blockIdx.x >> 8) & 1)) {
        __builtin_amdgcn_s_sleep(127);
    }

    const int tid  = threadIdx.x;
    const int wave = tid >> 6;
    const int lane = tid & 63;
    const int q    = lane >> 4;
    const int c    = lane & 15;
    const int row0 = blockIdx.x * BM;

    if (tid < E_NUM * L_DIM) phis[tid] = phi[tid];

    // ---- stage X tile: 8 rows per wave, all 8 loads in flight at once
    {
        float4 t0[8];
        #pragma unroll
        for (int i = 0; i < 8; ++i)
            t0[i] = *(const float4*)(X + (size_t)(row0 + wave * 8 + i) * F_DIM + lane * 4);
        #pragma unroll
        for (int i = 0; i < 8; ++i)
            *(uint2*)&Xs[(wave * 8 + i) * XK_STRIDE + lane * 4] = cvt4(t0[i]);
    }

    // prefetch ks=0 A-fragments (hide W1f L2 latency behind the barrier)
    bf16x8 af0[3];
    #pragma unroll
    for (int i = 0; i < 3; ++i)
        af0[i] = *(const bf16x8*)(W1f + ((size_t)((wave * 3 + i) * 8 + 0) * 64 + lane) * 8);

    __syncthreads();   // B1: Xs + phis ready

    // ================= GEMM1: D[n][m] = sum_k W1T[n][k] * Xs[m][k] =================
    // wave owns n-chunk of 48 (tiles wave*3 .. wave*3+2), all 4 m-tiles.
    f32x4 acc[3][4];
    #pragma unroll
    for (int i = 0; i < 3; ++i)
        #pragma unroll
        for (int j = 0; j < 4; ++j)
            acc[i][j] = (f32x4){0.f, 0.f, 0.f, 0.f};

    {   // ks = 0 (peeled, uses prefetched af0)
        bf16x8 bf0[4];
        #pragma unroll
        for (int j = 0; j < 4; ++j)
            bf0[j] = *(const bf16x8*)&Xs[(j * 16 + c) * XK_STRIDE + q * 8];
        #pragma unroll
        for (int i = 0; i < 3; ++i)
            #pragma unroll
            for (int j = 0; j < 4; ++j)
                acc[i][j] = __builtin_amdgcn_mfma_f32_16x16x32_bf16(af0[i], bf0[j], acc[i][j], 0, 0, 0);
    }
    #pragma unroll 2
    for (int ks = 1; ks < 8; ++ks) {
        bf16x8 af[3];
        #pragma unroll
        for (int i = 0; i < 3; ++i)
            af[i] = *(const bf16x8*)(W1f + ((size_t)((wave * 3 + i) * 8 + ks) * 64 + lane) * 8);
        bf16x8 bf_[4];
        #pragma unroll
        for (int j = 0; j < 4; ++j)
            bf_[j] = *(const bf16x8*)&Xs[(j * 16 + c) * XK_STRIDE + ks * 32 + q * 8];
        #pragma unroll
        for (int i = 0; i < 3; ++i)
            #pragma unroll
            for (int j = 0; j < 4; ++j)
                acc[i][j] = __builtin_amdgcn_mfma_f32_16x16x32_bf16(af[i], bf_[j], acc[i][j], 0, 0, 0);
    }
    __syncthreads();   // B2: Xs reads done; Hs (aliases) may be written

    // prefetch W2 fragments now -- in flight across the sigmoid phase + B3
    const int lt = wave >> 1;          // l-tile for GEMM2
    bf16x8 wfrag[12];
    #pragma unroll
    for (int ks = 0; ks < 12; ++ks)
        wfrag[ks] = *(const bf16x8*)(W2f + ((size_t)(lt * 12 + ks) * 64 + lane) * 8);

    #pragma unroll
    for (int i = 0; i < 3; ++i) {
        const int n0 = wave * 48 + i * 16 + q * 4;
        float4 bv = *(const float4*)(b1 + n0);
        #pragma unroll
        for (int j = 0; j < 4; ++j) {
            const int m = j * 16 + c;
            uint2 h2;
            h2.x = pk2(sigmoidf(acc[i][j][0] + bv.x), sigmoidf(acc[i][j][1] + bv.y));
            h2.y = pk2(sigmoidf(acc[i][j][2] + bv.z), sigmoidf(acc[i][j][3] + bv.w));
            *(uint2*)&Hs[m * H_STRIDE + n0] = h2;
        }
    }
    __syncthreads();   // B3: Hs complete

    // ================= GEMM2: D[l][m] = sum_h W2T[l][h] * Hs[m][h] =================
    // wave (lt = wave>>1) does l-tile lt, m-tiles {2*(wave&1), 2*(wave&1)+1}
    {
        const int mbase = (wave & 1) * 2;
        f32x4 acc2[2];
        acc2[0] = (f32x4){0.f, 0.f, 0.f, 0.f};
        acc2[1] = (f32x4){0.f, 0.f, 0.f, 0.f};
        #pragma unroll
        for (int ks = 0; ks < 12; ++ks) {
            #pragma unroll
            for (int j = 0; j < 2; ++j) {
                bf16x8 bf_ = *(const bf16x8*)&Hs[((mbase + j) * 16 + c) * H_STRIDE + ks * 32 + q * 8];
                acc2[j] = __builtin_amdgcn_mfma_f32_16x16x32_bf16(wfrag[ks], bf_, acc2[j], 0, 0, 0);
            }
        }
        const float4 b2v = *(const float4*)(b2 + lt * 16 + q * 4);
        #pragma unroll
        for (int j = 0; j < 2; ++j) {
            const int m = (mbase + j) * 16 + c;
            #pragma unroll
            for (int rg = 0; rg < 4; ++rg) {
                const int l = lt * 16 + q * 4 + rg;
                latT[l * LAT_STRIDE + m] = sigmoidf(acc2[j][rg] + ((const float*)&b2v)[rg]);
            }
        }
    }
    __syncthreads();   // B4: latT complete; Hs dead -> mus writable

    // pi fragments: prefetch on the GEMM3 waves (5..7) so the L2 latency
    // hides under the routing phase they'd otherwise idle through.
    bf16x8 pfrag[10];
    if (wave >= 5) {
        #pragma unroll
        for (int ks = 0; ks < 10; ++ks)
            pfrag[ks] = *(const bf16x8*)(piTf + ((size_t)ks * 64 + lane) * 8);
    }

    // ================= stage 3a: tree routing (waves 0..4) =================
    // wave e handles estimator e across all 64 rows (r = lane).
    if (wave < E_NUM) {
        const int e = wave;
        const int r = lane;
        float mu[64];
        mu[0] = 1.0f;
        #pragma unroll
        for (int lev = 0; lev < 6; ++lev) {
            const int w = 1 << lev;
            #pragma unroll
            for (int i = w - 1; i >= 0; --i) {
                float d = latT[phis[e * 64 + w + i] * LAT_STRIDE + r];
                float m = mu[i];
                mu[2 * i + 1] = m - m * d;
                mu[2 * i]     = m * d;
            }
        }
        #pragma unroll
        for (int j8 = 0; j8 < 8; ++j8) {
            bf16x8 v;
            #pragma unroll
            for (int t = 0; t < 4; ++t) {
                unsigned int p = pk2(mu[j8 * 8 + 2 * t], mu[j8 * 8 + 2 * t + 1]);
                v[2 * t]     = (short)(p & 0xFFFF);
                v[2 * t + 1] = (short)(p >> 16);
            }
            *((bf16x8*)&mus[r * MU_STRIDE + e * 64 + j8 * 8]) = v;
        }
    }
    __syncthreads();   // B5: mus complete

    // ================= stage 3b (waves 5..7): out[m][o] = sum_k mus[m][k]*piT[o][k]
    // wave 5 -> m-tiles 0 and 3; wave 6 -> 1; wave 7 -> 2.
    if (wave >= 5) {
        for (int mt = wave - 5; mt < 4; mt += (wave == 5 ? 3 : 4)) {
            f32x4 acc3 = (f32x4){0.f, 0.f, 0.f, 0.f};
            #pragma unroll
            for (int ks = 0; ks < 10; ++ks) {
                bf16x8 af = *((const bf16x8*)&mus[(mt * 16 + c) * MU_STRIDE + ks * 32 + q * 8]);
                acc3 = __builtin_amdgcn_mfma_f32_16x16x32_bf16(af, pfrag[ks], acc3, 0, 0, 0);
            }
            #pragma unroll
            for (int rg = 0; rg < 4; ++rg) {
                const int m = mt * 16 + q * 4 + rg;
                out[(size_t)(row0 + m) * O_DIM + c] = acc3[rg];
            }
        }
    }
}

extern "C" void kernel_launch(void* const* d_in, const int* in_sizes, int n_in,
                              void* d_out, int out_size, void* d_ws, size_t ws_size,
                              hipStream_t stream) {
    (void)in_sizes; (void)n_in; (void)out_size; (void)ws_size;
    const float* X  = (const float*)d_in[0];
    const float* W1 = (const float*)d_in[1];
    const float* b1 = (const float*)d_in[2];
    const float* W2 = (const float*)d_in[3];
    const float* b2 = (const float*)d_in[4];
    const int*   phi = (const int*)d_in[5];
    const float* pi  = (const float*)d_in[6];
    float* out = (float*)d_out;

    unsigned short* W1f  = (unsigned short*)d_ws;                           // 196608 B
    unsigned short* W2f  = (unsigned short*)((char*)d_ws + 196608);         //  49152 B
    unsigned short* piTf = (unsigned short*)((char*)d_ws + 196608 + 49152); //  10240 B

    prep_kernel<<<121, 256, 0, stream>>>(W1, W2, pi, W1f, W2f, piTf);

    const int nblocks = 131072 / BM;  // 2048
    fused_kernel<<<nblocks, 512, 0, stream>>>(X, W1f, b1, W2f, b2, phi, piTf, out);
}